// Round 9
// baseline (712.133 us; speedup 1.0000x reference)
//
#include <hip/hip_runtime.h>

#define H_ 128
#define W_ 128
#define B_ 8
#define CIN 64
#define COUT 128
#define KK 9
#define HW_ (H_*W_)
#define PIXB 32

typedef __bf16 bf16x8 __attribute__((ext_vector_type(8)));
typedef float f32x16 __attribute__((ext_vector_type(16)));
typedef unsigned short u16x8 __attribute__((ext_vector_type(8)));

__device__ inline unsigned short f2bf(float f) {
  unsigned int u = __builtin_bit_cast(unsigned int, f);
  u += 0x7FFFu + ((u >> 16) & 1u);   // RNE
  return (unsigned short)(u >> 16);
}
__device__ inline float bf2f(unsigned short h) {
  unsigned int u = ((unsigned int)h) << 16;
  return __builtin_bit_cast(float, u);
}

// ---------------- Kernel 0a: w_core -> MFMA-ready bf16 layout ----------------
// WT[cc0][kk][h][oc][i] = bf16(w_core[oc][cc0*16+h*8+i][kk]); 73728 entries.
__global__ __launch_bounds__(256) void wt_kernel(
    const float* __restrict__ w_core, unsigned short* __restrict__ WT) {
  int g = blockIdx.x * 256 + threadIdx.x;
  int i  = g & 7;
  int oc = (g >> 3) & 127;
  int h  = (g >> 10) & 1;
  int t  = g >> 11;
  int kk = t % 9;
  int cc0 = t / 9;
  int c = cc0 * 16 + h * 8 + i;
  WT[g] = f2bf(w_core[(size_t)oc * (CIN * KK) + c * KK + kk]);
}

// ---------------- Kernel 0b: w_off -> padded-32-row hi/lo bf16 layout --------
// WT2[cc0][kk][h][oc32][i]; rows >=18 zero. 18432 entries per plane.
__global__ __launch_bounds__(256) void wt2_kernel(
    const float* __restrict__ w_off, unsigned short* __restrict__ WT2h,
    unsigned short* __restrict__ WT2l) {
  int g = blockIdx.x * 256 + threadIdx.x;   // 18432 total
  int i  = g & 7;
  int oc = (g >> 3) & 31;
  int h  = (g >> 8) & 1;
  int t  = g >> 9;        // 0..35
  int kk = t % 9;
  int cc0 = t / 9;
  int c = cc0 * 16 + h * 8 + i;
  float v = (oc < 18) ? w_off[((size_t)oc * CIN + c) * 9 + kk] : 0.f;
  unsigned short hi = f2bf(v);
  WT2h[g] = hi;
  WT2l[g] = f2bf(v - bf2f(hi));
}

// ---------------- Fused kernel: offset conv + deformable conv ----------------
// Block = 256 thr = 4 waves = 32 pixels x (128 oc main / 18 oc offset).
// Grid 4096 = 8 batches x 512; bid&7 = batch -> per-XCD L2 holds one x[b].
// Phase 0: offset conv, K-split across waves (wave w = 16-ch chunk), reg gather,
//          3-term hi/lo MFMA, LDS reduce + bias -> offs LDS + global.
// Phase A: bilinear metadata from offs -> LDS -> hoisted to registers.
// Phase B: per-cc0 {deform gather -> s_hi/s_lo -> 2-term MFMA vs WT}.
__global__ __launch_bounds__(256, 4) void dcn_fused(
    const float* __restrict__ x, const unsigned short* __restrict__ WT,
    const unsigned short* __restrict__ WT2h, const unsigned short* __restrict__ WT2l,
    const float* __restrict__ b_off, float* __restrict__ offset_g,
    float* __restrict__ out) {
  // LDS pool: [0,18432) = s_hi(9216)+s_lo(9216), aliased by s_red (4*64*17*4=17408)
  //           [18432,20736) m_idx ; [20736,25344) m_w ; [25344,27648) offs
  __shared__ alignas(16) unsigned char lds_pool[27648];
  unsigned short* s_hi = (unsigned short*)lds_pool;
  unsigned short* s_lo = (unsigned short*)(lds_pool + 9216);
  float*   s_red = (float*)lds_pool;                       // phase-0 only
  ushort4* m_idx = (ushort4*)(lds_pool + 18432);
  float4*  m_w   = (float4*)(lds_pool + 20736);
  float*   offs  = (float*)(lds_pool + 25344);             // [18][32]

  const int tid = threadIdx.x;
  const int lane = tid & 63;
  const int wid = tid >> 6;
  const int b = blockIdx.x & 7;        // batch -> XCD affinity
  const int i = blockIdx.x >> 3;       // pixel-block within batch [0,512)
  const int ho = i >> 2;
  const int wo0 = (i & 3) * 32;
  const int pix = lane & 31;
  const int h_frag = lane >> 5;

  // ================= Phase 0: offset conv (wave wid owns channels wid*16..+16)
  {
    f32x16 oacc = {0.f,0.f,0.f,0.f,0.f,0.f,0.f,0.f,
                   0.f,0.f,0.f,0.f,0.f,0.f,0.f,0.f};
#pragma unroll
    for (int kk = 0; kk < KK; ++kk) {
      int ky = kk / 3, kx = kk % 3;
      int y = ho + ky - 1;
      int xx = wo0 + pix + kx - 1;
      bool v = (y >= 0) && (y < H_) && (xx >= 0) && (xx < W_);
      int yc = y < 0 ? 0 : (y > H_ - 1 ? H_ - 1 : y);
      int xc = xx < 0 ? 0 : (xx > W_ - 1 ? W_ - 1 : xx);
      const float* xp = x + ((size_t)(b * CIN + wid * 16 + h_frag * 8)) * HW_
                          + yc * W_ + xc;
      u16x8 bh, bl;
#pragma unroll
      for (int j = 0; j < 8; ++j) {
        float val = v ? xp[(size_t)j * HW_] : 0.f;
        unsigned short hi = f2bf(val);
        bh[j] = hi;
        bl[j] = f2bf(val - bf2f(hi));
      }
      size_t av = (size_t)(((wid * 9 + kk) * 2 + h_frag) * 32 + pix);
      bf16x8 ah = __builtin_bit_cast(bf16x8, ((const u16x8*)WT2h)[av]);
      bf16x8 al = __builtin_bit_cast(bf16x8, ((const u16x8*)WT2l)[av]);
      bf16x8 xh = __builtin_bit_cast(bf16x8, bh);
      bf16x8 xl = __builtin_bit_cast(bf16x8, bl);
      oacc = __builtin_amdgcn_mfma_f32_32x32x16_bf16(ah, xh, oacc, 0, 0, 0);
      oacc = __builtin_amdgcn_mfma_f32_32x32x16_bf16(ah, xl, oacc, 0, 0, 0);
      oacc = __builtin_amdgcn_mfma_f32_32x32x16_bf16(al, xh, oacc, 0, 0, 0);
    }
    // partials to LDS (pad 17 -> conflict-free)
#pragma unroll
    for (int r = 0; r < 16; ++r) s_red[(wid * 64 + lane) * 17 + r] = oacc[r];
  }
  __syncthreads();

  // ---- reduce 4 wave-partials + bias -> offs LDS + global offset output ----
  {
    int rl = tid & 63;
    int rg = tid >> 6;
#pragma unroll
    for (int q = 0; q < 4; ++q) {
      int r = rg * 4 + q;
      float s = s_red[(0 * 64 + rl) * 17 + r] + s_red[(1 * 64 + rl) * 17 + r]
              + s_red[(2 * 64 + rl) * 17 + r] + s_red[(3 * 64 + rl) * 17 + r];
      int oc = (r & 3) + 8 * (r >> 2) + 4 * (rl >> 5);
      int p = rl & 31;
      if (oc < 18) {
        float val = s + b_off[oc];
        offs[oc * 32 + p] = val;
        offset_g[(size_t)b * 18 * HW_ + (size_t)oc * HW_ + ho * W_ + wo0 + p] = val;
      }
    }
  }
  __syncthreads();

  // ================= Phase A: bilinear metadata (offsets from LDS) ==========
  for (int e = tid; e < PIXB * KK; e += 256) {
    int pe = e / KK, kk = e % KK;
    int ky = kk / 3, kx = kk % 3;
    float ody = offs[(kk * 2 + 0) * 32 + pe];
    float odx = offs[(kk * 2 + 1) * 32 + pe];
    float py = (float)(ho - 1 + ky) + ody;
    float px = (float)(wo0 + pe - 1 + kx) + odx;
    float y0f = floorf(py), x0f = floorf(px);
    float dy = py - y0f, dx = px - x0f;
    int y0 = (int)y0f, x0 = (int)x0f;
    int y1 = y0 + 1, x1 = x0 + 1;
    bool vy0 = (y0 >= 0) && (y0 < H_);
    bool vy1 = (y1 >= 0) && (y1 < H_);
    bool vx0 = (x0 >= 0) && (x0 < W_);
    bool vx1 = (x1 >= 0) && (x1 < W_);
    int cy0 = y0 < 0 ? 0 : (y0 > H_ - 1 ? H_ - 1 : y0);
    int cy1 = y1 < 0 ? 0 : (y1 > H_ - 1 ? H_ - 1 : y1);
    int cx0 = x0 < 0 ? 0 : (x0 > W_ - 1 ? W_ - 1 : x0);
    int cx1 = x1 < 0 ? 0 : (x1 > W_ - 1 ? W_ - 1 : x1);
    m_idx[e] = make_ushort4((unsigned short)(cy0 * W_ + cx0),
                            (unsigned short)(cy0 * W_ + cx1),
                            (unsigned short)(cy1 * W_ + cx0),
                            (unsigned short)(cy1 * W_ + cx1));
    m_w[e] = make_float4((1.f - dy) * (1.f - dx) * ((vy0 && vx0) ? 1.f : 0.f),
                         (1.f - dy) * dx         * ((vy0 && vx1) ? 1.f : 0.f),
                         dy * (1.f - dx)         * ((vy1 && vx0) ? 1.f : 0.f),
                         dy * dx                 * ((vy1 && vx1) ? 1.f : 0.f));
  }
  __syncthreads();

  // ---- hoist this thread's pixel metadata into registers ----
  const int gpix = tid & 31;
  const int gi = tid >> 5;
  ushort4 rid[9];
  float4  rwt[9];
#pragma unroll
  for (int kk = 0; kk < KK; ++kk) {
    rid[kk] = m_idx[gpix * KK + kk];
    rwt[kk] = m_w[gpix * KK + kk];
  }

  // ================= Phase B: deformable gather + main MFMA ================
  f32x16 acc = {0.f,0.f,0.f,0.f,0.f,0.f,0.f,0.f,
                0.f,0.f,0.f,0.f,0.f,0.f,0.f,0.f};
  const u16x8* wbase = (const u16x8*)WT + (size_t)(h_frag * COUT + wid * 32 + pix);

  for (int cc0 = 0; cc0 < 4; ++cc0) {
#pragma unroll
    for (int kk = 0; kk < KK; ++kk) {
      ushort4 id = rid[kk];
      float4 wt = rwt[kk];
#pragma unroll
      for (int hh = 0; hh < 2; ++hh) {
        int c = cc0 * 16 + hh * 8 + gi;
        const float* xp = x + ((size_t)(b * CIN + c)) * HW_;
        float v = wt.x * xp[id.x] + wt.y * xp[id.y] +
                  wt.z * xp[id.z] + wt.w * xp[id.w];
        unsigned short hi = f2bf(v);
        int e = ((kk * 2 + hh) * PIXB + gpix) * 8 + gi;
        s_hi[e] = hi;
        s_lo[e] = f2bf(v - bf2f(hi));
      }
    }
    __syncthreads();

    const u16x8* wp = wbase + (size_t)cc0 * (KK * 2 * COUT);
#pragma unroll
    for (int kk = 0; kk < KK; ++kk) {
      int sb = ((kk * 2 + h_frag) * PIXB + pix) * 8;
      bf16x8 a  = __builtin_bit_cast(bf16x8, wp[(size_t)kk * 2 * COUT]);
      bf16x8 bh = __builtin_bit_cast(bf16x8, *(const u16x8*)&s_hi[sb]);
      bf16x8 bl = __builtin_bit_cast(bf16x8, *(const u16x8*)&s_lo[sb]);
      acc = __builtin_amdgcn_mfma_f32_32x32x16_bf16(a, bh, acc, 0, 0, 0);
      acc = __builtin_amdgcn_mfma_f32_32x32x16_bf16(a, bl, acc, 0, 0, 0);
    }
    __syncthreads();
  }

  // ---- store main output: col=pix, row=(r&3)+8*(r>>2)+4*h_frag ----
  float* op = out + ((size_t)b * COUT) * HW_ + ho * W_ + wo0 + pix;
  const int ocb = wid * 32 + 4 * h_frag;
#pragma unroll
  for (int r = 0; r < 16; ++r) {
    int oc = ocb + (r & 3) + 8 * (r >> 2);
    op[(size_t)oc * HW_] = acc[r];
  }
}

extern "C" void kernel_launch(void* const* d_in, const int* in_sizes, int n_in,
                              void* d_out, int out_size, void* d_ws, size_t ws_size,
                              hipStream_t stream) {
  const float* x      = (const float*)d_in[0];
  const float* w_off  = (const float*)d_in[1];
  const float* b_off  = (const float*)d_in[2];
  const float* w_core = (const float*)d_in[3];
  float* offset = (float*)d_out;                         // [8,18,128,128]
  float* y      = (float*)d_out + (size_t)B_ * 18 * HW_; // [8,128,128,128]
  unsigned short* WT   = (unsigned short*)d_ws;          // 73728 u16
  unsigned short* WT2h = WT + 73728;                     // 18432 u16
  unsigned short* WT2l = WT2h + 18432;                   // 18432 u16

  wt_kernel<<<288, 256, 0, stream>>>(w_core, WT);
  wt2_kernel<<<72, 256, 0, stream>>>(w_off, WT2h, WT2l);
  dcn_fused<<<(B_ * HW_) / PIXB, 256, 0, stream>>>(x, WT, WT2h, WT2l, b_off,
                                                   offset, y);
}

// Round 10
// 591.417 us; speedup vs baseline: 1.2041x; 1.2041x over previous
//
#include <hip/hip_runtime.h>

#define H_ 128
#define W_ 128
#define B_ 8
#define CIN 64
#define COUT 128
#define KK 9
#define HW_ (H_*W_)
#define PIXB 32

typedef __bf16 bf16x8 __attribute__((ext_vector_type(8)));
typedef float f32x16 __attribute__((ext_vector_type(16)));
typedef unsigned short u16x8 __attribute__((ext_vector_type(8)));

__device__ inline unsigned short f2bf(float f) {
  unsigned int u = __builtin_bit_cast(unsigned int, f);
  u += 0x7FFFu + ((u >> 16) & 1u);   // RNE
  return (unsigned short)(u >> 16);
}
__device__ inline float bf2f(unsigned short h) {
  unsigned int u = ((unsigned int)h) << 16;
  return __builtin_bit_cast(float, u);
}

// ---------------- Kernel 0a: w_core -> MFMA-ready bf16 layout ----------------
__global__ __launch_bounds__(256) void wt_kernel(
    const float* __restrict__ w_core, unsigned short* __restrict__ WT) {
  int g = blockIdx.x * 256 + threadIdx.x;
  int i  = g & 7;
  int oc = (g >> 3) & 127;
  int h  = (g >> 10) & 1;
  int t  = g >> 11;
  int kk = t % 9;
  int cc0 = t / 9;
  int c = cc0 * 16 + h * 8 + i;
  WT[g] = f2bf(w_core[(size_t)oc * (CIN * KK) + c * KK + kk]);
}

// ---------------- Kernel 0b: w_off -> padded-32-row hi/lo bf16 layout --------
__global__ __launch_bounds__(256) void wt2_kernel(
    const float* __restrict__ w_off, unsigned short* __restrict__ WT2h,
    unsigned short* __restrict__ WT2l) {
  int g = blockIdx.x * 256 + threadIdx.x;   // 18432 total
  int i  = g & 7;
  int oc = (g >> 3) & 31;
  int h  = (g >> 8) & 1;
  int t  = g >> 9;        // 0..35
  int kk = t % 9;
  int cc0 = t / 9;
  int c = cc0 * 16 + h * 8 + i;
  float v = (oc < 18) ? w_off[((size_t)oc * CIN + c) * 9 + kk] : 0.f;
  unsigned short hi = f2bf(v);
  WT2h[g] = hi;
  WT2l[g] = f2bf(v - bf2f(hi));
}

// ---------------- Fused kernel: offset conv + deformable conv ----------------
// Block = 256 thr = 4 waves = 32 pixels x (128 oc main / 18 oc offset).
// Batch-major block order (b = bid>>9): co-resident blocks share one 4 MB
// x-slice -> L2-friendly (round-9 lesson: bid&7 "XCD swizzle" thrashed L2,
// FETCH 89->750 MB).  Gathers issue 24 loads (3 taps) into regs before any
// combine -> ~3x memory-level parallelism per wave (round-8: VGPR=44, few
// loads in flight, VALUBusy 20% = latency-bound).
__global__ __launch_bounds__(256, 4) void dcn_fused(
    const float* __restrict__ x, const unsigned short* __restrict__ WT,
    const unsigned short* __restrict__ WT2h, const unsigned short* __restrict__ WT2l,
    const float* __restrict__ b_off, float* __restrict__ offset_g,
    float* __restrict__ out) {
  // LDS pool: [0,18432) s_hi/s_lo, aliased by s_red (4*64*17*4=17408)
  //           [18432,20736) m_idx ; [20736,25344) m_w ; [25344,27648) offs
  __shared__ alignas(16) unsigned char lds_pool[27648];
  unsigned short* s_hi = (unsigned short*)lds_pool;
  unsigned short* s_lo = (unsigned short*)(lds_pool + 9216);
  float*   s_red = (float*)lds_pool;                       // phase-0 only
  ushort4* m_idx = (ushort4*)(lds_pool + 18432);
  float4*  m_w   = (float4*)(lds_pool + 20736);
  float*   offs  = (float*)(lds_pool + 25344);             // [18][32]

  const int tid = threadIdx.x;
  const int lane = tid & 63;
  const int wid = tid >> 6;
  const int b = blockIdx.x >> 9;       // batch-major: 512 blocks per batch
  const int i = blockIdx.x & 511;
  const int ho = i >> 2;
  const int wo0 = (i & 3) * 32;
  const int pix = lane & 31;
  const int h_frag = lane >> 5;

  // ================= Phase 0: offset conv (wave wid owns channels wid*16..+16)
  {
    f32x16 oacc = {0.f,0.f,0.f,0.f,0.f,0.f,0.f,0.f,
                   0.f,0.f,0.f,0.f,0.f,0.f,0.f,0.f};
#pragma unroll
    for (int kg = 0; kg < 3; ++kg) {
      float vx[3][8];
      // ---- issue 24 coalesced loads ----
#pragma unroll
      for (int kq = 0; kq < 3; ++kq) {
        int kk = kg * 3 + kq;
        int ky = kk / 3, kx = kk % 3;
        int y = ho + ky - 1;
        int xx = wo0 + pix + kx - 1;
        bool v = (y >= 0) && (y < H_) && (xx >= 0) && (xx < W_);
        int yc = y < 0 ? 0 : (y > H_ - 1 ? H_ - 1 : y);
        int xc = xx < 0 ? 0 : (xx > W_ - 1 ? W_ - 1 : xx);
        const float* xp = x + ((size_t)(b * CIN + wid * 16 + h_frag * 8)) * HW_
                            + yc * W_ + xc;
#pragma unroll
        for (int j = 0; j < 8; ++j)
          vx[kq][j] = v ? xp[(size_t)j * HW_] : 0.f;
      }
      // ---- convert + MFMA ----
#pragma unroll
      for (int kq = 0; kq < 3; ++kq) {
        int kk = kg * 3 + kq;
        u16x8 bh, bl;
#pragma unroll
        for (int j = 0; j < 8; ++j) {
          unsigned short hi = f2bf(vx[kq][j]);
          bh[j] = hi;
          bl[j] = f2bf(vx[kq][j] - bf2f(hi));
        }
        size_t av = (size_t)(((wid * 9 + kk) * 2 + h_frag) * 32 + pix);
        bf16x8 ah = __builtin_bit_cast(bf16x8, ((const u16x8*)WT2h)[av]);
        bf16x8 al = __builtin_bit_cast(bf16x8, ((const u16x8*)WT2l)[av]);
        bf16x8 xh = __builtin_bit_cast(bf16x8, bh);
        bf16x8 xl = __builtin_bit_cast(bf16x8, bl);
        oacc = __builtin_amdgcn_mfma_f32_32x32x16_bf16(ah, xh, oacc, 0, 0, 0);
        oacc = __builtin_amdgcn_mfma_f32_32x32x16_bf16(ah, xl, oacc, 0, 0, 0);
        oacc = __builtin_amdgcn_mfma_f32_32x32x16_bf16(al, xh, oacc, 0, 0, 0);
      }
    }
#pragma unroll
    for (int r = 0; r < 16; ++r) s_red[(wid * 64 + lane) * 17 + r] = oacc[r];
  }
  __syncthreads();

  // ---- reduce 4 wave-partials + bias -> offs LDS + global offset output ----
  {
    int rl = tid & 63;
    int rg = tid >> 6;
#pragma unroll
    for (int q = 0; q < 4; ++q) {
      int r = rg * 4 + q;
      float s = s_red[(0 * 64 + rl) * 17 + r] + s_red[(1 * 64 + rl) * 17 + r]
              + s_red[(2 * 64 + rl) * 17 + r] + s_red[(3 * 64 + rl) * 17 + r];
      int oc = (r & 3) + 8 * (r >> 2) + 4 * (rl >> 5);
      int p = rl & 31;
      if (oc < 18) {
        float val = s + b_off[oc];
        offs[oc * 32 + p] = val;
        offset_g[(size_t)b * 18 * HW_ + (size_t)oc * HW_ + ho * W_ + wo0 + p] = val;
      }
    }
  }
  __syncthreads();

  // ================= Phase A: bilinear metadata (offsets from LDS) ==========
  for (int e = tid; e < PIXB * KK; e += 256) {
    int pe = e / KK, kk = e % KK;
    int ky = kk / 3, kx = kk % 3;
    float ody = offs[(kk * 2 + 0) * 32 + pe];
    float odx = offs[(kk * 2 + 1) * 32 + pe];
    float py = (float)(ho - 1 + ky) + ody;
    float px = (float)(wo0 + pe - 1 + kx) + odx;
    float y0f = floorf(py), x0f = floorf(px);
    float dy = py - y0f, dx = px - x0f;
    int y0 = (int)y0f, x0 = (int)x0f;
    int y1 = y0 + 1, x1 = x0 + 1;
    bool vy0 = (y0 >= 0) && (y0 < H_);
    bool vy1 = (y1 >= 0) && (y1 < H_);
    bool vx0 = (x0 >= 0) && (x0 < W_);
    bool vx1 = (x1 >= 0) && (x1 < W_);
    int cy0 = y0 < 0 ? 0 : (y0 > H_ - 1 ? H_ - 1 : y0);
    int cy1 = y1 < 0 ? 0 : (y1 > H_ - 1 ? H_ - 1 : y1);
    int cx0 = x0 < 0 ? 0 : (x0 > W_ - 1 ? W_ - 1 : x0);
    int cx1 = x1 < 0 ? 0 : (x1 > W_ - 1 ? W_ - 1 : x1);
    m_idx[e] = make_ushort4((unsigned short)(cy0 * W_ + cx0),
                            (unsigned short)(cy0 * W_ + cx1),
                            (unsigned short)(cy1 * W_ + cx0),
                            (unsigned short)(cy1 * W_ + cx1));
    m_w[e] = make_float4((1.f - dy) * (1.f - dx) * ((vy0 && vx0) ? 1.f : 0.f),
                         (1.f - dy) * dx         * ((vy0 && vx1) ? 1.f : 0.f),
                         dy * (1.f - dx)         * ((vy1 && vx0) ? 1.f : 0.f),
                         dy * dx                 * ((vy1 && vx1) ? 1.f : 0.f));
  }
  __syncthreads();

  // ---- hoist this thread's pixel metadata into registers ----
  const int gpix = tid & 31;
  const int gi = tid >> 5;
  ushort4 rid[9];
  float4  rwt[9];
#pragma unroll
  for (int kk = 0; kk < KK; ++kk) {
    rid[kk] = m_idx[gpix * KK + kk];
    rwt[kk] = m_w[gpix * KK + kk];
  }

  // ================= Phase B: deformable gather + main MFMA ================
  f32x16 acc = {0.f,0.f,0.f,0.f,0.f,0.f,0.f,0.f,
                0.f,0.f,0.f,0.f,0.f,0.f,0.f,0.f};
  const u16x8* wbase = (const u16x8*)WT + (size_t)(h_frag * COUT + wid * 32 + pix);

  for (int cc0 = 0; cc0 < 4; ++cc0) {
#pragma unroll
    for (int kg = 0; kg < 3; ++kg) {
      float vc[3][2][4];   // 24 loads in flight
#pragma unroll
      for (int kq = 0; kq < 3; ++kq) {
        int kk = kg * 3 + kq;
        ushort4 id = rid[kk];
#pragma unroll
        for (int hh = 0; hh < 2; ++hh) {
          int c = cc0 * 16 + hh * 8 + gi;
          const float* xp = x + ((size_t)(b * CIN + c)) * HW_;
          vc[kq][hh][0] = xp[id.x];
          vc[kq][hh][1] = xp[id.y];
          vc[kq][hh][2] = xp[id.z];
          vc[kq][hh][3] = xp[id.w];
        }
      }
#pragma unroll
      for (int kq = 0; kq < 3; ++kq) {
        int kk = kg * 3 + kq;
        float4 wt = rwt[kk];
#pragma unroll
        for (int hh = 0; hh < 2; ++hh) {
          float v = wt.x * vc[kq][hh][0] + wt.y * vc[kq][hh][1] +
                    wt.z * vc[kq][hh][2] + wt.w * vc[kq][hh][3];
          unsigned short hi = f2bf(v);
          int e = ((kk * 2 + hh) * PIXB + gpix) * 8 + gi;
          s_hi[e] = hi;
          s_lo[e] = f2bf(v - bf2f(hi));
        }
      }
    }
    __syncthreads();

    const u16x8* wp = wbase + (size_t)cc0 * (KK * 2 * COUT);
#pragma unroll
    for (int kk = 0; kk < KK; ++kk) {
      int sb = ((kk * 2 + h_frag) * PIXB + pix) * 8;
      bf16x8 a  = __builtin_bit_cast(bf16x8, wp[(size_t)kk * 2 * COUT]);
      bf16x8 bh = __builtin_bit_cast(bf16x8, *(const u16x8*)&s_hi[sb]);
      bf16x8 bl = __builtin_bit_cast(bf16x8, *(const u16x8*)&s_lo[sb]);
      acc = __builtin_amdgcn_mfma_f32_32x32x16_bf16(a, bh, acc, 0, 0, 0);
      acc = __builtin_amdgcn_mfma_f32_32x32x16_bf16(a, bl, acc, 0, 0, 0);
    }
    __syncthreads();
  }

  // ---- store main output: col=pix, row=(r&3)+8*(r>>2)+4*h_frag ----
  float* op = out + ((size_t)b * COUT) * HW_ + ho * W_ + wo0 + pix;
  const int ocb = wid * 32 + 4 * h_frag;
#pragma unroll
  for (int r = 0; r < 16; ++r) {
    int oc = ocb + (r & 3) + 8 * (r >> 2);
    op[(size_t)oc * HW_] = acc[r];
  }
}

extern "C" void kernel_launch(void* const* d_in, const int* in_sizes, int n_in,
                              void* d_out, int out_size, void* d_ws, size_t ws_size,
                              hipStream_t stream) {
  const float* x      = (const float*)d_in[0];
  const float* w_off  = (const float*)d_in[1];
  const float* b_off  = (const float*)d_in[2];
  const float* w_core = (const float*)d_in[3];
  float* offset = (float*)d_out;                         // [8,18,128,128]
  float* y      = (float*)d_out + (size_t)B_ * 18 * HW_; // [8,128,128,128]
  unsigned short* WT   = (unsigned short*)d_ws;          // 73728 u16
  unsigned short* WT2h = WT + 73728;                     // 18432 u16
  unsigned short* WT2l = WT2h + 18432;                   // 18432 u16

  wt_kernel<<<288, 256, 0, stream>>>(w_core, WT);
  wt2_kernel<<<72, 256, 0, stream>>>(w_off, WT2h, WT2l);
  dcn_fused<<<(B_ * HW_) / PIXB, 256, 0, stream>>>(x, WT, WT2h, WT2l, b_off,
                                                   offset, y);
}

// Round 13
// 331.000 us; speedup vs baseline: 2.1515x; 1.7868x over previous
//
#include <hip/hip_runtime.h>

#define H_ 128
#define W_ 128
#define B_ 8
#define CIN 64
#define COUT 128
#define KK 9
#define HW_ (H_*W_)
#define PIXB 32

typedef __bf16 bf16x8 __attribute__((ext_vector_type(8)));
typedef float f32x16 __attribute__((ext_vector_type(16)));
typedef unsigned short u16x8 __attribute__((ext_vector_type(8)));

__device__ inline unsigned short f2bf(float f) {
  unsigned int u = __builtin_bit_cast(unsigned int, f);
  u += 0x7FFFu + ((u >> 16) & 1u);   // RNE
  return (unsigned short)(u >> 16);
}
__device__ inline float bf2f(unsigned short h) {
  unsigned int u = ((unsigned int)h) << 16;
  return __builtin_bit_cast(float, u);
}

// ---------------- Kernel 0a: w_core -> MFMA-ready bf16 layout ----------------
// WT[cc0][kk][h][oc][i] = bf16(w_core[oc][cc0*16+h*8+i][kk]); 73728 entries.
__global__ __launch_bounds__(256) void wt_kernel(
    const float* __restrict__ w_core, unsigned short* __restrict__ WT) {
  int g = blockIdx.x * 256 + threadIdx.x;
  int i  = g & 7;
  int oc = (g >> 3) & 127;
  int h  = (g >> 10) & 1;
  int t  = g >> 11;
  int kk = t % 9;
  int cc0 = t / 9;
  int c = cc0 * 16 + h * 8 + i;
  WT[g] = f2bf(w_core[(size_t)oc * (CIN * KK) + c * KK + kk]);
}

// ---------------- Kernel 0b: w_off -> padded-32-row hi/lo bf16 layout --------
// WT2[cc0][kk][h][oc32][i]; rows >=18 zero. 18432 entries per plane.
__global__ __launch_bounds__(256) void wt2_kernel(
    const float* __restrict__ w_off, unsigned short* __restrict__ WT2h,
    unsigned short* __restrict__ WT2l) {
  int g = blockIdx.x * 256 + threadIdx.x;   // 18432 total
  int i  = g & 7;
  int oc = (g >> 3) & 31;
  int h  = (g >> 8) & 1;
  int t  = g >> 9;        // 0..35
  int kk = t % 9;
  int cc0 = t / 9;
  int c = cc0 * 16 + h * 8 + i;
  float v = (oc < 18) ? w_off[((size_t)oc * CIN + c) * 9 + kk] : 0.f;
  unsigned short hi = f2bf(v);
  WT2h[g] = hi;
  WT2l[g] = f2bf(v - bf2f(hi));
}

// ---------------- Kernel 1: offset conv, MFMA, ZERO LDS ----------------
// 256 thr = 4 independent waves, each wave owns its own 32-px tile (no
// barriers, no reduce). Each lane direct-loads the 8 channels its own
// B-fragment needs. 3-term hi/lo split ~= fp32 exact. Bias in acc init.
__global__ __launch_bounds__(256) void offset_mfma2_kernel(
    const float* __restrict__ x, const unsigned short* __restrict__ WT2h,
    const unsigned short* __restrict__ WT2l, const float* __restrict__ b_off,
    float* __restrict__ offset_g) {
  const int lane = threadIdx.x & 63;
  const int wv = threadIdx.x >> 6;
  const int t = blockIdx.x * 4 + wv;       // tile id, batch-major
  const int p0 = t * PIXB;
  const int b = p0 / HW_;
  const int hw0 = p0 % HW_;
  const int ho = hw0 / W_;
  const int wo0 = hw0 % W_;
  const int pix = lane & 31;
  const int hf = lane >> 5;

  f32x16 acc;
#pragma unroll
  for (int r = 0; r < 16; ++r) {
    int oc = (r & 3) + 8 * (r >> 2) + 4 * hf;
    acc[r] = (oc < 18) ? b_off[oc] : 0.f;
  }

  for (int cc0 = 0; cc0 < 4; ++cc0) {
    const float* xbase = x + ((size_t)(b * CIN + cc0 * 16 + hf * 8)) * HW_;
#pragma unroll
    for (int kk = 0; kk < KK; ++kk) {
      int ky = kk / 3, kx = kk % 3;
      int y = ho + ky - 1;
      int xx = wo0 + pix + kx - 1;
      bool v = (y >= 0) && (y < H_) && (xx >= 0) && (xx < W_);
      int yc = y < 0 ? 0 : (y > H_ - 1 ? H_ - 1 : y);
      int xc = xx < 0 ? 0 : (xx > W_ - 1 ? W_ - 1 : xx);
      const float* xp = xbase + yc * W_ + xc;
      u16x8 bh, bl;
#pragma unroll
      for (int j = 0; j < 8; ++j) {
        float val = v ? xp[(size_t)j * HW_] : 0.f;
        unsigned short hi = f2bf(val);
        bh[j] = hi;
        bl[j] = f2bf(val - bf2f(hi));
      }
      size_t av = (size_t)(((cc0 * 9 + kk) * 2 + hf) * 32 + pix);
      bf16x8 ah = __builtin_bit_cast(bf16x8, ((const u16x8*)WT2h)[av]);
      bf16x8 al = __builtin_bit_cast(bf16x8, ((const u16x8*)WT2l)[av]);
      bf16x8 xh = __builtin_bit_cast(bf16x8, bh);
      bf16x8 xl = __builtin_bit_cast(bf16x8, bl);
      acc = __builtin_amdgcn_mfma_f32_32x32x16_bf16(ah, xh, acc, 0, 0, 0);
      acc = __builtin_amdgcn_mfma_f32_32x32x16_bf16(ah, xl, acc, 0, 0, 0);
      acc = __builtin_amdgcn_mfma_f32_32x32x16_bf16(al, xh, acc, 0, 0, 0);
    }
  }

  float* op = offset_g + (size_t)b * 18 * HW_ + ho * W_ + wo0 + pix;
#pragma unroll
  for (int r = 0; r < 16; ++r) {
    int oc = (r & 3) + 8 * (r >> 2) + 4 * hf;
    if (oc < 18) op[(size_t)oc * HW_] = acc[r];
  }
}

// ---------------- Kernel 2: deformable conv main (MFMA) ----------------
// EXACT round-8 kernel (measured 218 us, FETCH 89 MB): 4 waves, 32 px x 128 oc,
// pixel-major gather lanes, metadata in LDS, W-frags direct from L2-resident WT.
__global__ __launch_bounds__(256, 5) void dcn_main_mfma(
    const float* __restrict__ x, const float* __restrict__ offset,
    const unsigned short* __restrict__ WT, float* __restrict__ out) {
  __shared__ ushort4 m_idx[PIXB * KK];                             // 2304 B
  __shared__ float4  m_w[PIXB * KK];                               // 4608 B
  __shared__ alignas(16) unsigned short s_hi[KK * 2 * PIXB * 8];   // 9216 B
  __shared__ alignas(16) unsigned short s_lo[KK * 2 * PIXB * 8];   // 9216 B

  const int tid = threadIdx.x;
  const int lane = tid & 63;
  const int wid = tid >> 6;
  const int p0 = blockIdx.x * PIXB;
  const int b = p0 / HW_;
  const int hw0 = p0 % HW_;
  const int ho = hw0 / W_;
  const int wo0 = hw0 % W_;

  // Phase A: bilinear metadata per (pixel, tap)
  for (int e = tid; e < PIXB * KK; e += 256) {
    int pix = e / KK, kk = e % KK;
    int ky = kk / 3, kx = kk % 3;
    int wo = wo0 + pix;
    const float* offp = offset + ((size_t)b * 18 + kk * 2) * HW_ + ho * W_ + wo;
    float ody = offp[0];
    float odx = offp[HW_];
    float py = (float)(ho - 1 + ky) + ody;
    float px = (float)(wo - 1 + kx) + odx;
    float y0f = floorf(py), x0f = floorf(px);
    float dy = py - y0f, dx = px - x0f;
    int y0 = (int)y0f, x0 = (int)x0f;
    int y1 = y0 + 1, x1 = x0 + 1;
    bool vy0 = (y0 >= 0) && (y0 < H_);
    bool vy1 = (y1 >= 0) && (y1 < H_);
    bool vx0 = (x0 >= 0) && (x0 < W_);
    bool vx1 = (x1 >= 0) && (x1 < W_);
    int cy0 = y0 < 0 ? 0 : (y0 > H_ - 1 ? H_ - 1 : y0);
    int cy1 = y1 < 0 ? 0 : (y1 > H_ - 1 ? H_ - 1 : y1);
    int cx0 = x0 < 0 ? 0 : (x0 > W_ - 1 ? W_ - 1 : x0);
    int cx1 = x1 < 0 ? 0 : (x1 > W_ - 1 ? W_ - 1 : x1);
    m_idx[e] = make_ushort4((unsigned short)(cy0 * W_ + cx0),
                            (unsigned short)(cy0 * W_ + cx1),
                            (unsigned short)(cy1 * W_ + cx0),
                            (unsigned short)(cy1 * W_ + cx1));
    m_w[e] = make_float4((1.f - dy) * (1.f - dx) * ((vy0 && vx0) ? 1.f : 0.f),
                         (1.f - dy) * dx         * ((vy0 && vx1) ? 1.f : 0.f),
                         dy * (1.f - dx)         * ((vy1 && vx0) ? 1.f : 0.f),
                         dy * dx                 * ((vy1 && vx1) ? 1.f : 0.f));
  }
  __syncthreads();

  f32x16 acc = {0.f,0.f,0.f,0.f,0.f,0.f,0.f,0.f,
                0.f,0.f,0.f,0.f,0.f,0.f,0.f,0.f};

  const int gpix = tid & 31;   // gather: pixel (lane-major -> coalesced)
  const int gi = tid >> 5;     // gather: channel-low bits (i)
  const int h_frag = lane >> 5;
  const int col = lane & 31;

  // Per-wave A-fragment base in WT (vec-of-8 units)
  const u16x8* wbase = (const u16x8*)WT + (size_t)(h_frag * COUT + wid * 32 + col);

  for (int cc0 = 0; cc0 < 4; ++cc0) {
    // ---- gather S (hi/lo bf16) ----
#pragma unroll
    for (int kk = 0; kk < KK; ++kk) {
      ushort4 id = m_idx[gpix * KK + kk];
      float4 wt = m_w[gpix * KK + kk];
#pragma unroll
      for (int hh = 0; hh < 2; ++hh) {
        int c = cc0 * 16 + hh * 8 + gi;
        const float* xp = x + ((size_t)(b * CIN + c)) * HW_;
        float v = wt.x * xp[id.x] + wt.y * xp[id.y] +
                  wt.z * xp[id.z] + wt.w * xp[id.w];
        unsigned short hi = f2bf(v);
        int e = ((kk * 2 + hh) * PIXB + gpix) * 8 + gi;
        s_hi[e] = hi;
        s_lo[e] = f2bf(v - bf2f(hi));
      }
    }
    __syncthreads();

    // ---- MFMA: 9 kk x (hi + lo), A from global WT (coalesced, L2-hit) ----
    const u16x8* wp = wbase + (size_t)cc0 * (KK * 2 * COUT);
#pragma unroll
    for (int kk = 0; kk < KK; ++kk) {
      int sb = ((kk * 2 + h_frag) * PIXB + col) * 8;
      bf16x8 a  = __builtin_bit_cast(bf16x8, wp[(size_t)kk * 2 * COUT]);
      bf16x8 bh = __builtin_bit_cast(bf16x8, *(const u16x8*)&s_hi[sb]);
      bf16x8 bl = __builtin_bit_cast(bf16x8, *(const u16x8*)&s_lo[sb]);
      acc = __builtin_amdgcn_mfma_f32_32x32x16_bf16(a, bh, acc, 0, 0, 0);
      acc = __builtin_amdgcn_mfma_f32_32x32x16_bf16(a, bl, acc, 0, 0, 0);
    }
    __syncthreads();
  }

  // ---- store: D layout col=lane&31 (pix), row=(r&3)+8*(r>>2)+4*(lane>>5) ----
  float* op = out + ((size_t)b * COUT) * HW_ + ho * W_ + wo0 + col;
  const int ocb = wid * 32 + 4 * h_frag;
#pragma unroll
  for (int r = 0; r < 16; ++r) {
    int oc = ocb + (r & 3) + 8 * (r >> 2);
    op[(size_t)oc * HW_] = acc[r];
  }
}

extern "C" void kernel_launch(void* const* d_in, const int* in_sizes, int n_in,
                              void* d_out, int out_size, void* d_ws, size_t ws_size,
                              hipStream_t stream) {
  const float* x      = (const float*)d_in[0];
  const float* w_off  = (const float*)d_in[1];
  const float* b_off  = (const float*)d_in[2];
  const float* w_core = (const float*)d_in[3];
  float* offset = (float*)d_out;                         // [8,18,128,128]
  float* y      = (float*)d_out + (size_t)B_ * 18 * HW_; // [8,128,128,128]
  unsigned short* WT   = (unsigned short*)d_ws;          // 73728 u16
  unsigned short* WT2h = WT + 73728;                     // 18432 u16
  unsigned short* WT2l = WT2h + 18432;                   // 18432 u16

  wt_kernel<<<288, 256, 0, stream>>>(w_core, WT);
  wt2_kernel<<<72, 256, 0, stream>>>(w_off, WT2h, WT2l);
  offset_mfma2_kernel<<<(B_ * HW_) / PIXB / 4, 256, 0, stream>>>(x, WT2h, WT2l,
                                                                 b_off, offset);
  dcn_main_mfma<<<(B_ * HW_) / PIXB, 256, 0, stream>>>(x, offset, WT, y);
}